// Round 1
// baseline (304.862 us; speedup 1.0000x reference)
//
#include <hip/hip_runtime.h>
#include <hip/hip_bf16.h>
#include <cstdint>

typedef __attribute__((ext_vector_type(8))) short bf16x8;
typedef __attribute__((ext_vector_type(4))) float f32x4;
typedef __attribute__((ext_vector_type(2))) int i32x2;

#define NCOL 8192

// ---- workspace layout ----
// uint16 region (bf16 weights, fragment-ordered):
//   AW  [64 m][4 kc][4 qd][8]              -> 8192 el
//   A1  [6 h][64 m][2 kc][4 qd][8]         -> 24576 el
//   AF  [6 h][16 m][2 kc][4 qd][8] (padded)-> 6144 el
// f32 region (starts at float index 19456):
//   OFSH[64]  OFH[384]  BIAS[16]
#define WS_AW 0
#define WS_A1 8192
#define WS_AF 32768
#define WS_U16_TOTAL 38912
#define WS_OFSH 19456
#define WS_OFH  19520
#define WS_BIAS 19904
#define PREP_TOTAL (WS_U16_TOTAL + 464)

union FragU { uint32_t u[4]; bf16x8 v; uint4 q; };

__device__ __forceinline__ uint16_t f2bf(float f) {
  uint32_t x = __builtin_bit_cast(uint32_t, f);
  x += 0x7fffu + ((x >> 16) & 1u);
  return (uint16_t)(x >> 16);
}
__device__ __forceinline__ uint32_t rne_bits(float f) {
  uint32_t x = __builtin_bit_cast(uint32_t, f);
  return x + 0x7fffu + ((x >> 16) & 1u);
}
// pack (lo, hi) -> dword with bf16(lo) in low16: 2x v_add3 + 1x v_perm
__device__ __forceinline__ uint32_t pack_bf16(float lo, float hi) {
  return __builtin_amdgcn_perm(rne_bits(hi), rne_bits(lo), 0x07060302u);
}

// C-frag -> B-frag cross-lane remap, in registers (no LDS).
// Input (per lane, lane group g = lane>>4):
//   lo = packed channels (32*kc    + 4g + 2u, +1)  [C-frag of mt=2kc]
//   hi = packed channels (32*kc+16 + 4g + 2u, +1)  [C-frag of mt=2kc+1]
// Output at dest group qd:
//   f1 = channels 32*kc + 8*qd + 2u      -> B-frag dword u
//   f2 = channels 32*kc + 8*qd + 4 + 2u  -> B-frag dword u+2
// Derivation: 32swap gives t0=[X0,X1,Y0,Y1], t1=[X2,X3,Y2,Y3] (by 16-lane group);
// 16swap(t0,t1) gives f1=[X0,X2,Y0,Y2], f2=[X1,X3,Y1,Y3].
__device__ __forceinline__ void cswap(uint32_t lo, uint32_t hi,
                                      uint32_t& f1, uint32_t& f2) {
  i32x2 t = __builtin_amdgcn_permlane32_swap((int)lo, (int)hi, false, false);
  i32x2 f = __builtin_amdgcn_permlane16_swap(t[0], t[1], false, false);
  f1 = (uint32_t)f[0];
  f2 = (uint32_t)f[1];
}

// ---------------- prep: fold BN into weights, convert to bf16, frag layout ----------------
__global__ __launch_bounds__(256) void ch_prep(
    const float* __restrict__ shw, const float* __restrict__ shb,
    const float* __restrict__ shg, const float* __restrict__ shbeta,
    const float* __restrict__ shmean, const float* __restrict__ shvar,
    const float* __restrict__ w1, const float* __restrict__ b1,
    const float* __restrict__ g1, const float* __restrict__ beta1,
    const float* __restrict__ mean1, const float* __restrict__ var1,
    const float* __restrict__ hm_w, const float* __restrict__ hm_b,
    const float* __restrict__ reg_w, const float* __restrict__ reg_b,
    const float* __restrict__ height_w, const float* __restrict__ height_b,
    const float* __restrict__ dim_w, const float* __restrict__ dim_b,
    const float* __restrict__ rot_w, const float* __restrict__ rot_b,
    const float* __restrict__ iou_w, const float* __restrict__ iou_b,
    uint16_t* __restrict__ wsq)
{
  const int e = blockIdx.x * 256 + threadIdx.x;
  if (e >= PREP_TOTAL) return;
  const int rowbase[6] = {0, 3, 5, 6, 9, 11};
  const int couts[6]   = {3, 2, 1, 3, 2, 1};
  const float* wfp[6]  = {hm_w, reg_w, height_w, dim_w, rot_w, iou_w};

  if (e < WS_A1) {                       // AW: e = 128m + 32kc + 8q + i
    const int i = e & 7, q = (e >> 3) & 3, kc = (e >> 5) & 3, m = e >> 7;
    const int k = kc * 32 + q * 8 + i;
    const float sc = shg[m] * rsqrtf(shvar[m] + 1e-5f);
    wsq[e] = f2bf(shw[m * 128 + k] * sc);
  } else if (e < WS_AF) {                // A1: e2 = 4096h + 64m + 32kc + 8q + i
    const int e2 = e - WS_A1;
    const int i = e2 & 7, q = (e2 >> 3) & 3, kc = (e2 >> 5) & 1,
              m = (e2 >> 6) & 63, h = e2 >> 12;
    const int k = kc * 32 + q * 8 + i, row = h * 64 + m;
    const float sc = g1[row] * rsqrtf(var1[row] + 1e-5f);
    wsq[e] = f2bf(w1[row * 64 + k] * sc);
  } else if (e < WS_U16_TOTAL) {         // AF: e2 = 1024h + 64m + 32kc + 8q + i
    const int e2 = e - WS_AF;
    const int i = e2 & 7, q = (e2 >> 3) & 3, kc = (e2 >> 5) & 1,
              m = (e2 >> 6) & 15, h = e2 >> 10;
    const int k = kc * 32 + q * 8 + i, rr = m - rowbase[h];
    const float v = (rr >= 0 && rr < couts[h]) ? wfp[h][rr * 64 + k] : 0.f;
    wsq[e] = f2bf(v);
  } else {                               // f32 params
    const int t2 = e - WS_U16_TOTAL;
    float* wff = (float*)wsq;
    float v = 0.f;
    if (t2 < 64) {
      const float sc = shg[t2] * rsqrtf(shvar[t2] + 1e-5f);
      v = (shb[t2] - shmean[t2]) * sc + shbeta[t2];
    } else if (t2 < 448) {
      const int i = t2 - 64;
      const float sc = g1[i] * rsqrtf(var1[i] + 1e-5f);
      v = (b1[i] - mean1[i]) * sc + beta1[i];
    } else {
      const int i = t2 - 448;
      if (i < 3)       v = hm_b[i];
      else if (i < 5)  v = reg_b[i - 3];
      else if (i < 6)  v = height_b[i - 5];
      else if (i < 9)  v = dim_b[i - 6];
      else if (i < 11) v = rot_b[i - 9];
      else if (i < 12) v = iou_b[i - 11];
    }
    wff[WS_OFSH + t2] = v;
  }
}

// ---------------- main: fused 3-stage, zero LDS, zero barriers ----------------
// Y and Z never leave registers: the C-frag -> B-frag layout change is done with
// permlane32_swap + permlane16_swap instead of an LDS round trip.
__global__ __launch_bounds__(256, 5) void ch_main(
    const float* __restrict__ ct,
    const uint16_t* __restrict__ wsq,
    const float* __restrict__ wsf,
    float* __restrict__ outp)
{
  const int t    = threadIdx.x;
  const int wv   = t >> 6;
  const int lane = t & 63;
  const int l15  = lane & 15;
  const int qd   = lane >> 4;
  const int bid  = blockIdx.x;
  const int b    = bid >> 6;
  const int col0 = (bid & 63) * 128;
  const int nb   = wv * 32;

  const float* ctb = ct + (size_t)b * 128 * NCOL;
  const int voff0 = qd * 8 * NCOL + col0 + nb + l15;  // lane-varying part of X addr

  // ---- stage 1: Y = (sc.*shw) @ X ; B-frags straight from global ----
  f32x4 accY[4][2];
  #pragma unroll
  for (int mt = 0; mt < 4; ++mt)
    #pragma unroll
    for (int j = 0; j < 2; ++j)
      accY[mt][j] = (f32x4){0.f, 0.f, 0.f, 0.f};

  #pragma unroll
  for (int kc = 0; kc < 4; ++kc) {
    bf16x8 a[4];
    #pragma unroll
    for (int mt = 0; mt < 4; ++mt) {
      FragU fa;
      fa.q = *(const uint4*)(wsq + WS_AW + ((mt * 16 + l15) * 4 + kc) * 32 + qd * 8);
      a[mt] = fa.v;
    }
    #pragma unroll
    for (int j = 0; j < 2; ++j) {
      FragU f;
      #pragma unroll
      for (int i2 = 0; i2 < 4; ++i2) {
        const size_t off = (size_t)((kc * 32 + 2 * i2) * NCOL) + voff0 + j * 16;
        f.u[i2] = pack_bf16(ctb[off], ctb[off + NCOL]);
      }
      #pragma unroll
      for (int mt = 0; mt < 4; ++mt)
        accY[mt][j] = __builtin_amdgcn_mfma_f32_16x16x32_bf16(a[mt], f.v, accY[mt][j], 0, 0, 0);
    }
  }

  // stage-1 epilogue: offset + ReLU + pack + permlane remap -> persistent Y B-frags
  FragU yfrag[2][2];  // [kc][j], 16 VGPRs, reused by all 6 heads
  #pragma unroll
  for (int j = 0; j < 2; ++j) {
    uint32_t P[4][2];
    #pragma unroll
    for (int mt = 0; mt < 4; ++mt) {
      const f32x4 of = *(const f32x4*)(wsf + WS_OFSH + mt * 16 + qd * 4);
      const f32x4 v = accY[mt][j];
      P[mt][0] = pack_bf16(fmaxf(v[0] + of[0], 0.f), fmaxf(v[1] + of[1], 0.f));
      P[mt][1] = pack_bf16(fmaxf(v[2] + of[2], 0.f), fmaxf(v[3] + of[3], 0.f));
    }
    #pragma unroll
    for (int kc = 0; kc < 2; ++kc)
      #pragma unroll
      for (int u = 0; u < 2; ++u)
        cswap(P[2 * kc][u], P[2 * kc + 1][u],
              yfrag[kc][j].u[u], yfrag[kc][j].u[u + 2]);
  }

  // ---- heads ----
  f32x4 accO[2];
  accO[0] = (f32x4){0.f, 0.f, 0.f, 0.f};
  accO[1] = (f32x4){0.f, 0.f, 0.f, 0.f};

  #pragma unroll
  for (int h = 0; h < 6; ++h) {
    // stage 2: Z = (sc1.*W1[h]) @ Y  (B operand straight from registers)
    f32x4 accZ[4][2];
    #pragma unroll
    for (int mt = 0; mt < 4; ++mt)
      #pragma unroll
      for (int j = 0; j < 2; ++j)
        accZ[mt][j] = (f32x4){0.f, 0.f, 0.f, 0.f};

    #pragma unroll
    for (int kc = 0; kc < 2; ++kc) {
      bf16x8 a[4];
      #pragma unroll
      for (int mt = 0; mt < 4; ++mt) {
        FragU fa;
        fa.q = *(const uint4*)(wsq + WS_A1 + ((h * 64 + mt * 16 + l15) * 2 + kc) * 32 + qd * 8);
        a[mt] = fa.v;
      }
      #pragma unroll
      for (int j = 0; j < 2; ++j)
        #pragma unroll
        for (int mt = 0; mt < 4; ++mt)
          accZ[mt][j] = __builtin_amdgcn_mfma_f32_16x16x32_bf16(a[mt], yfrag[kc][j].v, accZ[mt][j], 0, 0, 0);
    }

    // stage-3 A-frags (zero-padded 16-row weights)
    FragU af[2];
    #pragma unroll
    for (int kc = 0; kc < 2; ++kc)
      af[kc].q = *(const uint4*)(wsq + WS_AF + ((h * 16 + l15) * 2 + kc) * 32 + qd * 8);

    // per-j: offset + ReLU + pack + permlane remap -> Z B-frags; stage 3 MFMA
    #pragma unroll
    for (int j = 0; j < 2; ++j) {
      uint32_t Q[4][2];
      #pragma unroll
      for (int mt = 0; mt < 4; ++mt) {
        const f32x4 of = *(const f32x4*)(wsf + WS_OFH + h * 64 + mt * 16 + qd * 4);
        const f32x4 v = accZ[mt][j];
        Q[mt][0] = pack_bf16(fmaxf(v[0] + of[0], 0.f), fmaxf(v[1] + of[1], 0.f));
        Q[mt][1] = pack_bf16(fmaxf(v[2] + of[2], 0.f), fmaxf(v[3] + of[3], 0.f));
      }
      FragU zf[2];
      #pragma unroll
      for (int kc = 0; kc < 2; ++kc)
        #pragma unroll
        for (int u = 0; u < 2; ++u)
          cswap(Q[2 * kc][u], Q[2 * kc + 1][u], zf[kc].u[u], zf[kc].u[u + 2]);

      #pragma unroll
      for (int kc = 0; kc < 2; ++kc)
        accO[j] = __builtin_amdgcn_mfma_f32_16x16x32_bf16(af[kc].v, zf[kc].v, accO[j], 0, 0, 0);
    }
  }

  // ---- epilogue: bias + store rows 0..11 (f32 out) ----
  if (qd < 3) {
    const f32x4 bs = *(const f32x4*)(wsf + WS_BIAS + qd * 4);
    #pragma unroll
    for (int j = 0; j < 2; ++j) {
      const int col = col0 + nb + j * 16 + l15;
      #pragma unroll
      for (int r = 0; r < 4; ++r)
        outp[((size_t)(b * 12 + qd * 4 + r)) * NCOL + col] = accO[j][r] + bs[r];
    }
  }
}

extern "C" void kernel_launch(void* const* d_in, const int* in_sizes, int n_in,
                              void* d_out, int out_size, void* d_ws, size_t ws_size,
                              hipStream_t stream) {
  (void)out_size; (void)ws_size;
  // d_in is in setup_inputs() dict order (round-5 verified); sorted fallback kept.
  static const int sortedPos[25] = {
      0, 24, 19, 21, 20, 22, 23, 8, 3, 5, 4, 6, 7,
      12, 11, 16, 15, 10, 9, 2, 1, 18, 17, 14, 13};
  const bool sorted_order =
      (n_in == 25) && (in_sizes[1] == 3) && (in_sizes[2] == 192) &&
      (in_sizes[8] == 24576) && (in_sizes[24] == 8192);
  const float* p[25];
  for (int r = 0; r < 25; ++r)
    p[r] = (const float*)d_in[sorted_order ? sortedPos[r] : r];

  uint16_t* wsq = (uint16_t*)d_ws;   // needs 79,680 B of d_ws

  hipLaunchKernelGGL(ch_prep, dim3((PREP_TOTAL + 255) / 256), dim3(256), 0, stream,
      p[1], p[2], p[3], p[4], p[5], p[6],
      p[7], p[8], p[9], p[10], p[11], p[12],
      p[13], p[14], p[15], p[16], p[17], p[18],
      p[19], p[20], p[21], p[22], p[23], p[24],
      wsq);

  hipLaunchKernelGGL(ch_main, dim3(2048), dim3(256), 0, stream,
      p[0], (const uint16_t*)wsq, (const float*)wsq, (float*)d_out);
}

// Round 2
// 294.832 us; speedup vs baseline: 1.0340x; 1.0340x over previous
//
#include <hip/hip_runtime.h>
#include <hip/hip_bf16.h>
#include <cstdint>

typedef __attribute__((ext_vector_type(8))) short bf16x8;
typedef __attribute__((ext_vector_type(4))) float f32x4;
typedef __attribute__((ext_vector_type(2))) int i32x2;

#define NCOL 8192

// ---- workspace layout ----
// uint16 region (bf16 weights, fragment-ordered):
//   AW  [64 m][4 kc][4 qd][8]              -> 8192 el
//   A1  [6 h][64 m][2 kc][4 qd][8]         -> 24576 el
//   AF  [6 h][16 m][2 kc][4 qd][8] (padded)-> 6144 el
// f32 region (starts at float index 19456):
//   OFSH[64]  OFH[384]  BIAS[16]
#define WS_AW 0
#define WS_A1 8192
#define WS_AF 32768
#define WS_U16_TOTAL 38912
#define WS_OFSH 19456
#define WS_OFH  19520
#define WS_BIAS 19904
#define PREP_TOTAL (WS_U16_TOTAL + 464)

union FragU { uint32_t u[4]; bf16x8 v; uint4 q; };

__device__ __forceinline__ uint16_t f2bf(float f) {
  uint32_t x = __builtin_bit_cast(uint32_t, f);
  x += 0x7fffu + ((x >> 16) & 1u);
  return (uint16_t)(x >> 16);
}
__device__ __forceinline__ uint32_t rne_bits(float f) {
  uint32_t x = __builtin_bit_cast(uint32_t, f);
  return x + 0x7fffu + ((x >> 16) & 1u);
}
// pack (lo, hi) -> dword with bf16(lo) in low16: 2x v_add3 + 1x v_perm
__device__ __forceinline__ uint32_t pack_bf16(float lo, float hi) {
  return __builtin_amdgcn_perm(rne_bits(hi), rne_bits(lo), 0x07060302u);
}

// C-frag -> B-frag cross-lane remap, in registers (no LDS).
// Derivation: 32swap gives t0=[X0,X1,Y0,Y1], t1=[X2,X3,Y2,Y3] (by 16-lane group);
// 16swap(t0,t1) gives f1=[X0,X2,Y0,Y2], f2=[X1,X3,Y1,Y3].
__device__ __forceinline__ void cswap(uint32_t lo, uint32_t hi,
                                      uint32_t& f1, uint32_t& f2) {
  i32x2 t = __builtin_amdgcn_permlane32_swap((int)lo, (int)hi, false, false);
  i32x2 f = __builtin_amdgcn_permlane16_swap(t[0], t[1], false, false);
  f1 = (uint32_t)f[0];
  f2 = (uint32_t)f[1];
}

// ---------------- prep: fold BN into weights, convert to bf16, frag layout ----------------
__global__ __launch_bounds__(256) void ch_prep(
    const float* __restrict__ shw, const float* __restrict__ shb,
    const float* __restrict__ shg, const float* __restrict__ shbeta,
    const float* __restrict__ shmean, const float* __restrict__ shvar,
    const float* __restrict__ w1, const float* __restrict__ b1,
    const float* __restrict__ g1, const float* __restrict__ beta1,
    const float* __restrict__ mean1, const float* __restrict__ var1,
    const float* __restrict__ hm_w, const float* __restrict__ hm_b,
    const float* __restrict__ reg_w, const float* __restrict__ reg_b,
    const float* __restrict__ height_w, const float* __restrict__ height_b,
    const float* __restrict__ dim_w, const float* __restrict__ dim_b,
    const float* __restrict__ rot_w, const float* __restrict__ rot_b,
    const float* __restrict__ iou_w, const float* __restrict__ iou_b,
    uint16_t* __restrict__ wsq)
{
  const int e = blockIdx.x * 256 + threadIdx.x;
  if (e >= PREP_TOTAL) return;
  const int rowbase[6] = {0, 3, 5, 6, 9, 11};
  const int couts[6]   = {3, 2, 1, 3, 2, 1};
  const float* wfp[6]  = {hm_w, reg_w, height_w, dim_w, rot_w, iou_w};

  if (e < WS_A1) {                       // AW: e = 128m + 32kc + 8q + i
    const int i = e & 7, q = (e >> 3) & 3, kc = (e >> 5) & 3, m = e >> 7;
    const int k = kc * 32 + q * 8 + i;
    const float sc = shg[m] * rsqrtf(shvar[m] + 1e-5f);
    wsq[e] = f2bf(shw[m * 128 + k] * sc);
  } else if (e < WS_AF) {                // A1: e2 = 4096h + 64m + 32kc + 8q + i
    const int e2 = e - WS_A1;
    const int i = e2 & 7, q = (e2 >> 3) & 3, kc = (e2 >> 5) & 1,
              m = (e2 >> 6) & 63, h = e2 >> 12;
    const int k = kc * 32 + q * 8 + i, row = h * 64 + m;
    const float sc = g1[row] * rsqrtf(var1[row] + 1e-5f);
    wsq[e] = f2bf(w1[row * 64 + k] * sc);
  } else if (e < WS_U16_TOTAL) {         // AF: e2 = 1024h + 64m + 32kc + 8q + i
    const int e2 = e - WS_AF;
    const int i = e2 & 7, q = (e2 >> 3) & 3, kc = (e2 >> 5) & 1,
              m = (e2 >> 6) & 15, h = e2 >> 10;
    const int k = kc * 32 + q * 8 + i, rr = m - rowbase[h];
    const float v = (rr >= 0 && rr < couts[h]) ? wfp[h][rr * 64 + k] : 0.f;
    wsq[e] = f2bf(v);
  } else {                               // f32 params
    const int t2 = e - WS_U16_TOTAL;
    float* wff = (float*)wsq;
    float v = 0.f;
    if (t2 < 64) {
      const float sc = shg[t2] * rsqrtf(shvar[t2] + 1e-5f);
      v = (shb[t2] - shmean[t2]) * sc + shbeta[t2];
    } else if (t2 < 448) {
      const int i = t2 - 64;
      const float sc = g1[i] * rsqrtf(var1[i] + 1e-5f);
      v = (b1[i] - mean1[i]) * sc + beta1[i];
    } else {
      const int i = t2 - 448;
      if (i < 3)       v = hm_b[i];
      else if (i < 5)  v = reg_b[i - 3];
      else if (i < 6)  v = height_b[i - 5];
      else if (i < 9)  v = dim_b[i - 6];
      else if (i < 11) v = rot_b[i - 9];
      else if (i < 12) v = iou_b[i - 11];
    }
    wff[WS_OFSH + t2] = v;
  }
}

// ---------------- main: fused 3-stage, zero LDS, zero barriers ----------------
// Y and Z never leave registers (permlane C->B remap). Head loop is ROLLED
// (#pragma unroll 1): the fully-unrolled version was ~35 KB of straight-line
// code, exceeding the 32 KB per-CU I-cache -- every wave streamed the whole
// body through L2 I-fetches, which no occupancy can hide. Rolled body fits I$.
__global__ __launch_bounds__(256, 4) void ch_main(
    const float* __restrict__ ct,
    const uint16_t* __restrict__ wsq,
    const float* __restrict__ wsf,
    float* __restrict__ outp)
{
  const int t    = threadIdx.x;
  const int wv   = t >> 6;
  const int lane = t & 63;
  const int l15  = lane & 15;
  const int qd   = lane >> 4;
  const int bid  = blockIdx.x;
  const int b    = bid >> 6;
  const int col0 = (bid & 63) * 128;
  const int nb   = wv * 32;

  const float* ctb = ct + (size_t)b * 128 * NCOL;
  const int voff0 = qd * 8 * NCOL + col0 + nb + l15;  // lane-varying part of X addr

  // ---- stage 1: Y = (sc.*shw) @ X ; B-frags straight from global ----
  f32x4 accY[4][2];
  #pragma unroll
  for (int mt = 0; mt < 4; ++mt)
    #pragma unroll
    for (int j = 0; j < 2; ++j)
      accY[mt][j] = (f32x4){0.f, 0.f, 0.f, 0.f};

  #pragma unroll
  for (int kc = 0; kc < 4; ++kc) {
    bf16x8 a[4];
    #pragma unroll
    for (int mt = 0; mt < 4; ++mt) {
      FragU fa;
      fa.q = *(const uint4*)(wsq + WS_AW + ((mt * 16 + l15) * 4 + kc) * 32 + qd * 8);
      a[mt] = fa.v;
    }
    #pragma unroll
    for (int j = 0; j < 2; ++j) {
      FragU f;
      #pragma unroll
      for (int i2 = 0; i2 < 4; ++i2) {
        const size_t off = (size_t)((kc * 32 + 2 * i2) * NCOL) + voff0 + j * 16;
        f.u[i2] = pack_bf16(ctb[off], ctb[off + NCOL]);
      }
      #pragma unroll
      for (int mt = 0; mt < 4; ++mt)
        accY[mt][j] = __builtin_amdgcn_mfma_f32_16x16x32_bf16(a[mt], f.v, accY[mt][j], 0, 0, 0);
    }
  }

  // stage-1 epilogue: offset + ReLU + pack + permlane remap -> persistent Y B-frags
  FragU yfrag[2][2];  // [kc][j], 16 VGPRs, reused by all 6 heads
  #pragma unroll
  for (int j = 0; j < 2; ++j) {
    uint32_t P[4][2];
    #pragma unroll
    for (int mt = 0; mt < 4; ++mt) {
      const f32x4 of = *(const f32x4*)(wsf + WS_OFSH + mt * 16 + qd * 4);
      const f32x4 v = accY[mt][j];
      P[mt][0] = pack_bf16(fmaxf(v[0] + of[0], 0.f), fmaxf(v[1] + of[1], 0.f));
      P[mt][1] = pack_bf16(fmaxf(v[2] + of[2], 0.f), fmaxf(v[3] + of[3], 0.f));
    }
    #pragma unroll
    for (int kc = 0; kc < 2; ++kc)
      #pragma unroll
      for (int u = 0; u < 2; ++u)
        cswap(P[2 * kc][u], P[2 * kc + 1][u],
              yfrag[kc][j].u[u], yfrag[kc][j].u[u + 2]);
  }

  // ---- heads (ROLLED loop: keep code resident in I-cache) ----
  f32x4 accO[2];
  accO[0] = (f32x4){0.f, 0.f, 0.f, 0.f};
  accO[1] = (f32x4){0.f, 0.f, 0.f, 0.f};

  // per-head base pointers (advanced at loop end)
  const uint16_t* a1p = wsq + WS_A1 + l15 * 64 + qd * 8;   // + h*4096
  const uint16_t* afp = wsq + WS_AF + l15 * 64 + qd * 8;   // + h*1024
  const float*    ofp = wsf + WS_OFH + qd * 4;             // + h*64

  #pragma unroll 1
  for (int h = 0; h < 6; ++h) {
    // stage 2: Z = (sc1.*W1[h]) @ Y  (B operand straight from registers)
    f32x4 accZ[4][2];
    #pragma unroll
    for (int mt = 0; mt < 4; ++mt)
      #pragma unroll
      for (int j = 0; j < 2; ++j)
        accZ[mt][j] = (f32x4){0.f, 0.f, 0.f, 0.f};

    #pragma unroll
    for (int kc = 0; kc < 2; ++kc) {
      bf16x8 a[4];
      #pragma unroll
      for (int mt = 0; mt < 4; ++mt) {
        FragU fa;
        fa.q = *(const uint4*)(a1p + mt * 1024 + kc * 32);
        a[mt] = fa.v;
      }
      #pragma unroll
      for (int j = 0; j < 2; ++j)
        #pragma unroll
        for (int mt = 0; mt < 4; ++mt)
          accZ[mt][j] = __builtin_amdgcn_mfma_f32_16x16x32_bf16(a[mt], yfrag[kc][j].v, accZ[mt][j], 0, 0, 0);
    }

    // stage-3 A-frags (zero-padded 16-row weights)
    FragU af[2];
    #pragma unroll
    for (int kc = 0; kc < 2; ++kc)
      af[kc].q = *(const uint4*)(afp + kc * 32);

    // per-j: offset + ReLU + pack + permlane remap -> Z B-frags; stage 3 MFMA
    #pragma unroll
    for (int j = 0; j < 2; ++j) {
      uint32_t Q[4][2];
      #pragma unroll
      for (int mt = 0; mt < 4; ++mt) {
        const f32x4 of = *(const f32x4*)(ofp + mt * 16);
        const f32x4 v = accZ[mt][j];
        Q[mt][0] = pack_bf16(fmaxf(v[0] + of[0], 0.f), fmaxf(v[1] + of[1], 0.f));
        Q[mt][1] = pack_bf16(fmaxf(v[2] + of[2], 0.f), fmaxf(v[3] + of[3], 0.f));
      }
      FragU zf[2];
      #pragma unroll
      for (int kc = 0; kc < 2; ++kc)
        #pragma unroll
        for (int u = 0; u < 2; ++u)
          cswap(Q[2 * kc][u], Q[2 * kc + 1][u], zf[kc].u[u], zf[kc].u[u + 2]);

      #pragma unroll
      for (int kc = 0; kc < 2; ++kc)
        accO[j] = __builtin_amdgcn_mfma_f32_16x16x32_bf16(af[kc].v, zf[kc].v, accO[j], 0, 0, 0);
    }

    a1p += 4096;
    afp += 1024;
    ofp += 64;
  }

  // ---- epilogue: bias + store rows 0..11 (f32 out) ----
  if (qd < 3) {
    const f32x4 bs = *(const f32x4*)(wsf + WS_BIAS + qd * 4);
    #pragma unroll
    for (int j = 0; j < 2; ++j) {
      const int col = col0 + nb + j * 16 + l15;
      #pragma unroll
      for (int r = 0; r < 4; ++r)
        outp[((size_t)(b * 12 + qd * 4 + r)) * NCOL + col] = accO[j][r] + bs[r];
    }
  }
}

extern "C" void kernel_launch(void* const* d_in, const int* in_sizes, int n_in,
                              void* d_out, int out_size, void* d_ws, size_t ws_size,
                              hipStream_t stream) {
  (void)out_size; (void)ws_size;
  // d_in is in setup_inputs() dict order (round-5 verified); sorted fallback kept.
  static const int sortedPos[25] = {
      0, 24, 19, 21, 20, 22, 23, 8, 3, 5, 4, 6, 7,
      12, 11, 16, 15, 10, 9, 2, 1, 18, 17, 14, 13};
  const bool sorted_order =
      (n_in == 25) && (in_sizes[1] == 3) && (in_sizes[2] == 192) &&
      (in_sizes[8] == 24576) && (in_sizes[24] == 8192);
  const float* p[25];
  for (int r = 0; r < 25; ++r)
    p[r] = (const float*)d_in[sorted_order ? sortedPos[r] : r];

  uint16_t* wsq = (uint16_t*)d_ws;   // needs 79,680 B of d_ws

  hipLaunchKernelGGL(ch_prep, dim3((PREP_TOTAL + 255) / 256), dim3(256), 0, stream,
      p[1], p[2], p[3], p[4], p[5], p[6],
      p[7], p[8], p[9], p[10], p[11], p[12],
      p[13], p[14], p[15], p[16], p[17], p[18],
      p[19], p[20], p[21], p[22], p[23], p[24],
      wsq);

  hipLaunchKernelGGL(ch_main, dim3(2048), dim3(256), 0, stream,
      p[0], (const uint16_t*)wsq, (const float*)wsq, (float*)d_out);
}

// Round 3
// 290.641 us; speedup vs baseline: 1.0489x; 1.0144x over previous
//
#include <hip/hip_runtime.h>
#include <hip/hip_bf16.h>
#include <cstdint>

typedef __attribute__((ext_vector_type(8))) short bf16x8;
typedef __attribute__((ext_vector_type(4))) float f32x4;
typedef __attribute__((ext_vector_type(2))) int i32x2;

#define NCOL 8192

// ---- workspace layout ----
// uint16 region (bf16 weights, fragment-ordered):
//   AW  [64 m][4 kc][4 qd][8]              -> 8192 el
//   A1  [6 h][64 m][2 kc][4 qd][8]         -> 24576 el
//   AF  [6 h][16 m][2 kc][4 qd][8] (padded)-> 6144 el
// f32 region (starts at float index 19456):
//   OFSH[64]  OFH[384]  BIAS[16]
#define WS_AW 0
#define WS_A1 8192
#define WS_AF 32768
#define WS_U16_TOTAL 38912
#define WS_OFSH 19456
#define WS_OFH  19520
#define WS_BIAS 19904
#define PREP_TOTAL (WS_U16_TOTAL + 464)

union FragU { uint32_t u[4]; bf16x8 v; uint4 q; };

__device__ __forceinline__ uint16_t f2bf(float f) {
  uint32_t x = __builtin_bit_cast(uint32_t, f);
  x += 0x7fffu + ((x >> 16) & 1u);
  return (uint16_t)(x >> 16);
}
__device__ __forceinline__ uint32_t rne_bits(float f) {
  uint32_t x = __builtin_bit_cast(uint32_t, f);
  return x + 0x7fffu + ((x >> 16) & 1u);
}
// pack (lo, hi) -> dword with bf16(lo) in low16: 2x v_add3 + 1x v_perm
__device__ __forceinline__ uint32_t pack_bf16(float lo, float hi) {
  return __builtin_amdgcn_perm(rne_bits(hi), rne_bits(lo), 0x07060302u);
}

// C-frag -> B-frag cross-lane remap, in registers (no LDS).
// Derivation: 32swap gives t0=[X0,X1,Y0,Y1], t1=[X2,X3,Y2,Y3] (by 16-lane group);
// 16swap(t0,t1) gives f1=[X0,X2,Y0,Y2], f2=[X1,X3,Y1,Y3].
__device__ __forceinline__ void cswap(uint32_t lo, uint32_t hi,
                                      uint32_t& f1, uint32_t& f2) {
  i32x2 t = __builtin_amdgcn_permlane32_swap((int)lo, (int)hi, false, false);
  i32x2 f = __builtin_amdgcn_permlane16_swap(t[0], t[1], false, false);
  f1 = (uint32_t)f[0];
  f2 = (uint32_t)f[1];
}

// ---------------- prep: fold BN into weights, convert to bf16, frag layout ----------------
__global__ __launch_bounds__(256) void ch_prep(
    const float* __restrict__ shw, const float* __restrict__ shb,
    const float* __restrict__ shg, const float* __restrict__ shbeta,
    const float* __restrict__ shmean, const float* __restrict__ shvar,
    const float* __restrict__ w1, const float* __restrict__ b1,
    const float* __restrict__ g1, const float* __restrict__ beta1,
    const float* __restrict__ mean1, const float* __restrict__ var1,
    const float* __restrict__ hm_w, const float* __restrict__ hm_b,
    const float* __restrict__ reg_w, const float* __restrict__ reg_b,
    const float* __restrict__ height_w, const float* __restrict__ height_b,
    const float* __restrict__ dim_w, const float* __restrict__ dim_b,
    const float* __restrict__ rot_w, const float* __restrict__ rot_b,
    const float* __restrict__ iou_w, const float* __restrict__ iou_b,
    uint16_t* __restrict__ wsq)
{
  const int e = blockIdx.x * 256 + threadIdx.x;
  if (e >= PREP_TOTAL) return;
  const int rowbase[6] = {0, 3, 5, 6, 9, 11};
  const int couts[6]   = {3, 2, 1, 3, 2, 1};
  const float* wfp[6]  = {hm_w, reg_w, height_w, dim_w, rot_w, iou_w};

  if (e < WS_A1) {                       // AW: e = 128m + 32kc + 8q + i
    const int i = e & 7, q = (e >> 3) & 3, kc = (e >> 5) & 3, m = e >> 7;
    const int k = kc * 32 + q * 8 + i;
    const float sc = shg[m] * rsqrtf(shvar[m] + 1e-5f);
    wsq[e] = f2bf(shw[m * 128 + k] * sc);
  } else if (e < WS_AF) {                // A1: e2 = 4096h + 64m + 32kc + 8q + i
    const int e2 = e - WS_A1;
    const int i = e2 & 7, q = (e2 >> 3) & 3, kc = (e2 >> 5) & 1,
              m = (e2 >> 6) & 63, h = e2 >> 12;
    const int k = kc * 32 + q * 8 + i, row = h * 64 + m;
    const float sc = g1[row] * rsqrtf(var1[row] + 1e-5f);
    wsq[e] = f2bf(w1[row * 64 + k] * sc);
  } else if (e < WS_U16_TOTAL) {         // AF: e2 = 1024h + 64m + 32kc + 8q + i
    const int e2 = e - WS_AF;
    const int i = e2 & 7, q = (e2 >> 3) & 3, kc = (e2 >> 5) & 1,
              m = (e2 >> 6) & 15, h = e2 >> 10;
    const int k = kc * 32 + q * 8 + i, rr = m - rowbase[h];
    const float v = (rr >= 0 && rr < couts[h]) ? wfp[h][rr * 64 + k] : 0.f;
    wsq[e] = f2bf(v);
  } else {                               // f32 params
    const int t2 = e - WS_U16_TOTAL;
    float* wff = (float*)wsq;
    float v = 0.f;
    if (t2 < 64) {
      const float sc = shg[t2] * rsqrtf(shvar[t2] + 1e-5f);
      v = (shb[t2] - shmean[t2]) * sc + shbeta[t2];
    } else if (t2 < 448) {
      const int i = t2 - 64;
      const float sc = g1[i] * rsqrtf(var1[i] + 1e-5f);
      v = (b1[i] - mean1[i]) * sc + beta1[i];
    } else {
      const int i = t2 - 448;
      if (i < 3)       v = hm_b[i];
      else if (i < 5)  v = reg_b[i - 3];
      else if (i < 6)  v = height_b[i - 5];
      else if (i < 9)  v = dim_b[i - 6];
      else if (i < 11) v = rot_b[i - 9];
      else if (i < 12) v = iou_b[i - 11];
    }
    wff[WS_OFSH + t2] = v;
  }
}

// ---------------- main: fused 3-stage, zero LDS, zero barriers ----------------
// Y and Z never leave registers (permlane C->B remap). Head loop ROLLED (I$).
// This round: explicit load batching for memory-level parallelism.
// Previous builds had VGPR_Count=52 -- the compiler register-minimized and
// serialized ~64 global loads at ~600 cy each (L3-resident input). Here all
// stage-1 X values are preloaded into a 64-reg array (one vmcnt drain instead
// of ~32), and each head's 10 weight loads are batched at the head-loop top.
// __launch_bounds__(256,3): 170-VGPR budget so the X buffer cannot spill.
__global__ __launch_bounds__(256, 3) void ch_main(
    const float* __restrict__ ct,
    const uint16_t* __restrict__ wsq,
    const float* __restrict__ wsf,
    float* __restrict__ outp)
{
  const int t    = threadIdx.x;
  const int wv   = t >> 6;
  const int lane = t & 63;
  const int l15  = lane & 15;
  const int qd   = lane >> 4;
  const int bid  = blockIdx.x;
  const int b    = bid >> 6;
  const int col0 = (bid & 63) * 128;
  const int nb   = wv * 32;

  const float* ctb = ct + (size_t)b * 128 * NCOL;
  const int voff0 = qd * 8 * NCOL + col0 + nb + l15;  // lane-varying part of X addr

  // ---- stage 1: preload ALL X values (64 loads in flight), then pack+MFMA ----
  float xv[4][2][8];  // [kc][j][2*i2+d] -- statically indexed => registers
  #pragma unroll
  for (int kc = 0; kc < 4; ++kc)
    #pragma unroll
    for (int j = 0; j < 2; ++j)
      #pragma unroll
      for (int i2 = 0; i2 < 4; ++i2) {
        const size_t off = (size_t)((kc * 32 + 2 * i2) * NCOL) + voff0 + j * 16;
        xv[kc][j][2 * i2]     = ctb[off];
        xv[kc][j][2 * i2 + 1] = ctb[off + NCOL];
      }
  __builtin_amdgcn_sched_barrier(0);  // don't sink the loads into the consume chain

  f32x4 accY[4][2];
  #pragma unroll
  for (int mt = 0; mt < 4; ++mt)
    #pragma unroll
    for (int j = 0; j < 2; ++j)
      accY[mt][j] = (f32x4){0.f, 0.f, 0.f, 0.f};

  #pragma unroll
  for (int kc = 0; kc < 4; ++kc) {
    bf16x8 a[4];
    #pragma unroll
    for (int mt = 0; mt < 4; ++mt) {
      FragU fa;
      fa.q = *(const uint4*)(wsq + WS_AW + ((mt * 16 + l15) * 4 + kc) * 32 + qd * 8);
      a[mt] = fa.v;
    }
    #pragma unroll
    for (int j = 0; j < 2; ++j) {
      FragU f;
      #pragma unroll
      for (int i2 = 0; i2 < 4; ++i2)
        f.u[i2] = pack_bf16(xv[kc][j][2 * i2], xv[kc][j][2 * i2 + 1]);
      #pragma unroll
      for (int mt = 0; mt < 4; ++mt)
        accY[mt][j] = __builtin_amdgcn_mfma_f32_16x16x32_bf16(a[mt], f.v, accY[mt][j], 0, 0, 0);
    }
  }

  // stage-1 epilogue: offset + ReLU + pack + permlane remap -> persistent Y B-frags
  FragU yfrag[2][2];  // [kc][j], 16 VGPRs, reused by all 6 heads
  #pragma unroll
  for (int j = 0; j < 2; ++j) {
    uint32_t P[4][2];
    #pragma unroll
    for (int mt = 0; mt < 4; ++mt) {
      const f32x4 of = *(const f32x4*)(wsf + WS_OFSH + mt * 16 + qd * 4);
      const f32x4 v = accY[mt][j];
      P[mt][0] = pack_bf16(fmaxf(v[0] + of[0], 0.f), fmaxf(v[1] + of[1], 0.f));
      P[mt][1] = pack_bf16(fmaxf(v[2] + of[2], 0.f), fmaxf(v[3] + of[3], 0.f));
    }
    #pragma unroll
    for (int kc = 0; kc < 2; ++kc)
      #pragma unroll
      for (int u = 0; u < 2; ++u)
        cswap(P[2 * kc][u], P[2 * kc + 1][u],
              yfrag[kc][j].u[u], yfrag[kc][j].u[u + 2]);
  }

  // ---- heads (ROLLED loop; all weight loads batched at iteration top) ----
  f32x4 accO[2];
  accO[0] = (f32x4){0.f, 0.f, 0.f, 0.f};
  accO[1] = (f32x4){0.f, 0.f, 0.f, 0.f};

  const uint16_t* a1p = wsq + WS_A1 + l15 * 64 + qd * 8;   // + h*4096
  const uint16_t* afp = wsq + WS_AF + l15 * 64 + qd * 8;   // + h*1024
  const float*    ofp = wsf + WS_OFH + qd * 4;             // + h*64

  #pragma unroll 1
  for (int h = 0; h < 6; ++h) {
    // batch ALL loads for this head: 8 stage-2 A-frags + 2 stage-3 A-frags + 4 offsets
    FragU wa[2][4];   // [kc][mt]
    FragU af[2];
    f32x4 ofv[4];
    #pragma unroll
    for (int kc = 0; kc < 2; ++kc)
      #pragma unroll
      for (int mt = 0; mt < 4; ++mt)
        wa[kc][mt].q = *(const uint4*)(a1p + mt * 1024 + kc * 32);
    #pragma unroll
    for (int kc = 0; kc < 2; ++kc)
      af[kc].q = *(const uint4*)(afp + kc * 32);
    #pragma unroll
    for (int mt = 0; mt < 4; ++mt)
      ofv[mt] = *(const f32x4*)(ofp + mt * 16);
    __builtin_amdgcn_sched_barrier(0);

    // stage 2: Z = (sc1.*W1[h]) @ Y  (B operand straight from registers)
    f32x4 accZ[4][2];
    #pragma unroll
    for (int mt = 0; mt < 4; ++mt)
      #pragma unroll
      for (int j = 0; j < 2; ++j)
        accZ[mt][j] = (f32x4){0.f, 0.f, 0.f, 0.f};

    #pragma unroll
    for (int kc = 0; kc < 2; ++kc)
      #pragma unroll
      for (int j = 0; j < 2; ++j)
        #pragma unroll
        for (int mt = 0; mt < 4; ++mt)
          accZ[mt][j] = __builtin_amdgcn_mfma_f32_16x16x32_bf16(wa[kc][mt].v, yfrag[kc][j].v, accZ[mt][j], 0, 0, 0);

    // per-j: offset + ReLU + pack + permlane remap -> Z B-frags; stage 3 MFMA
    #pragma unroll
    for (int j = 0; j < 2; ++j) {
      uint32_t Q[4][2];
      #pragma unroll
      for (int mt = 0; mt < 4; ++mt) {
        const f32x4 v = accZ[mt][j];
        Q[mt][0] = pack_bf16(fmaxf(v[0] + ofv[mt][0], 0.f), fmaxf(v[1] + ofv[mt][1], 0.f));
        Q[mt][1] = pack_bf16(fmaxf(v[2] + ofv[mt][2], 0.f), fmaxf(v[3] + ofv[mt][3], 0.f));
      }
      FragU zf[2];
      #pragma unroll
      for (int kc = 0; kc < 2; ++kc)
        #pragma unroll
        for (int u = 0; u < 2; ++u)
          cswap(Q[2 * kc][u], Q[2 * kc + 1][u], zf[kc].u[u], zf[kc].u[u + 2]);

      #pragma unroll
      for (int kc = 0; kc < 2; ++kc)
        accO[j] = __builtin_amdgcn_mfma_f32_16x16x32_bf16(af[kc].v, zf[kc].v, accO[j], 0, 0, 0);
    }

    a1p += 4096;
    afp += 1024;
    ofp += 64;
  }

  // ---- epilogue: bias + store rows 0..11 (f32 out) ----
  if (qd < 3) {
    const f32x4 bs = *(const f32x4*)(wsf + WS_BIAS + qd * 4);
    #pragma unroll
    for (int j = 0; j < 2; ++j) {
      const int col = col0 + nb + j * 16 + l15;
      #pragma unroll
      for (int r = 0; r < 4; ++r)
        outp[((size_t)(b * 12 + qd * 4 + r)) * NCOL + col] = accO[j][r] + bs[r];
    }
  }
}

extern "C" void kernel_launch(void* const* d_in, const int* in_sizes, int n_in,
                              void* d_out, int out_size, void* d_ws, size_t ws_size,
                              hipStream_t stream) {
  (void)out_size; (void)ws_size;
  // d_in is in setup_inputs() dict order (round-5 verified); sorted fallback kept.
  static const int sortedPos[25] = {
      0, 24, 19, 21, 20, 22, 23, 8, 3, 5, 4, 6, 7,
      12, 11, 16, 15, 10, 9, 2, 1, 18, 17, 14, 13};
  const bool sorted_order =
      (n_in == 25) && (in_sizes[1] == 3) && (in_sizes[2] == 192) &&
      (in_sizes[8] == 24576) && (in_sizes[24] == 8192);
  const float* p[25];
  for (int r = 0; r < 25; ++r)
    p[r] = (const float*)d_in[sorted_order ? sortedPos[r] : r];

  uint16_t* wsq = (uint16_t*)d_ws;   // needs 79,680 B of d_ws

  hipLaunchKernelGGL(ch_prep, dim3((PREP_TOTAL + 255) / 256), dim3(256), 0, stream,
      p[1], p[2], p[3], p[4], p[5], p[6],
      p[7], p[8], p[9], p[10], p[11], p[12],
      p[13], p[14], p[15], p[16], p[17], p[18],
      p[19], p[20], p[21], p[22], p[23], p[24],
      wsq);

  hipLaunchKernelGGL(ch_main, dim3(2048), dim3(256), 0, stream,
      p[0], (const uint16_t*)wsq, (const float*)wsq, (float*)d_out);
}